// Round 3
// baseline (845.793 us; speedup 1.0000x reference)
//
#include <hip/hip_runtime.h>
#include <hip/hip_fp16.h>

// Problem constants (IndyLSTM: B=32, T=2048, I=H=512)
#define B_  32
#define T_  2048
#define H_  512
#define K_  512          // input size I (GEMM K)
#define N_  2048         // 4*H (GEMM N), column index n' = h*4 + g  (g: 0=f,1=i,2=o,3=c)

typedef __attribute__((ext_vector_type(8)))  __bf16 bf16x8;
typedef __attribute__((ext_vector_type(4)))  __bf16 bf16x4;
typedef __attribute__((ext_vector_type(4)))  float  floatx4;
typedef __attribute__((ext_vector_type(16))) float  floatx16;

// ---------------- conversion kernels (split bf16: v = hi + lo, fp32-accurate) ----------------

__global__ void convert_x(const float* __restrict__ x,
                          __bf16* __restrict__ xh, __bf16* __restrict__ xl, int n4) {
    int i = blockIdx.x * blockDim.x + threadIdx.x;
    if (i < n4) {
        const float4 v = ((const float4*)x)[i];
        bf16x4 hi, lo;
        hi[0] = (__bf16)v.x; lo[0] = (__bf16)(v.x - (float)hi[0]);
        hi[1] = (__bf16)v.y; lo[1] = (__bf16)(v.y - (float)hi[1]);
        hi[2] = (__bf16)v.z; lo[2] = (__bf16)(v.z - (float)hi[2]);
        hi[3] = (__bf16)v.w; lo[3] = (__bf16)(v.w - (float)hi[3]);
        *(bf16x4*)(xh + 4 * (size_t)i) = hi;
        *(bf16x4*)(xl + 4 * (size_t)i) = lo;
    }
}

// Wt[n'][k] = W_g[k][h] with n' = h*4+g  (k-contiguous => "B^T" layout for GEMM)
__global__ void convert_w(const float* __restrict__ Wf, const float* __restrict__ Wi,
                          const float* __restrict__ Wo, const float* __restrict__ Wc,
                          __bf16* __restrict__ Wh, __bf16* __restrict__ Wl) {
    int o = blockIdx.x * blockDim.x + threadIdx.x;   // [0, N_*K_)
    int k = o & (K_ - 1);
    int n = o >> 9;          // n' in [0,2048)
    int g = n & 3, h = n >> 2;
    const float* W = (g == 0) ? Wf : (g == 1) ? Wi : (g == 2) ? Wo : Wc;
    float v = W[k * H_ + h];
    __bf16 hi = (__bf16)v;
    Wh[o] = hi;
    Wl[o] = (__bf16)(v - (float)hi);
}

// ---------------- split-bf16 MFMA GEMM ----------------
// C[m][n] = sum_k A[m][k]*Bt[n][k] with A ~ Ah+Al, Bt ~ Bh+Bl
// acc += Ah*Bh + Ah*Bl + Al*Bh   (fp32-accurate to ~2^-18 relative); C stored fp16
//
// Round-3:
//  (a) MFMA shape 16x16x32 -> 32x32x16: same FLOPs in 24 instead of 48 MFMA/iter,
//      194 vs 233 cy matrix-pipe (m119: 2495 vs 2075 TF ceiling). Same LDS, same
//      ds_read bytes, same register budget.
//  (b) T1 bijective XCD swizzle (nwg=8192 % 8 == 0): each XCD gets a contiguous
//      1024-block chunk -> disjoint bm ranges per XCD, A panels L2-resident;
//      attacks the stage-load latency that bounds this 2-barrier structure.
//  (kept from R2) zero-conflict staging/read swizzle, single-buffered 32KB LDS.
#define BM 128
#define BN 128
#define BK 32
#define NWG ((B_ * T_ / BM) * (N_ / BN))   // 8192

__device__ __forceinline__ void async_copy16(const __bf16* g, __bf16* l) {
    __builtin_amdgcn_global_load_lds(
        (const __attribute__((address_space(1))) void*)g,
        (__attribute__((address_space(3))) void*)l,
        16, 0, 0);
}

__global__ __launch_bounds__(256, 2)
void gemm_bt(const __bf16* __restrict__ Ah, const __bf16* __restrict__ Al,
             const __bf16* __restrict__ Bh, const __bf16* __restrict__ Bl,
             __half* __restrict__ C) {
    __shared__ __align__(16) __bf16 AsH[BM * BK];
    __shared__ __align__(16) __bf16 AsL[BM * BK];
    __shared__ __align__(16) __bf16 BsH[BN * BK];
    __shared__ __align__(16) __bf16 BsL[BN * BK];

    const int tid  = threadIdx.x;
    const int lane = tid & 63;
    const int wave = tid >> 6;

    // T1: bijective XCD-aware remap (consecutive swz stay on one XCD)
    const int bid = blockIdx.x;
    const int swz = (bid & 7) * (NWG / 8) + (bid >> 3);
    const int ntiles = N_ / BN;                 // 16
    const int bm = swz / ntiles;
    const int bn = swz % ntiles;
    const int m0 = bm * BM, n0 = bn * BN;

    const int waveM = (wave & 1) * 64;
    const int waveN = (wave >> 1) * 64;

    // 32x32x16 fragment addressing: A/B row = lane&31, k = (lane>>5)*8 + j
    const int lr = lane & 31;                   // row within a 32-row block
    const int kc = lane >> 5;                   // base k-chunk (0 or 1)
    const int sw = (lr >> 1) & 3;               // read-side XOR swizzle term

    floatx16 acc[2][2] = {};

    // staging: tile = 512 x 16B chunks; thread handles chunks tid and tid+256.
    // chunk c -> row c>>2, lds col-chunk c&3; SOURCE col-chunk is XOR-swizzled
    // (same swizzle valid for rows r and r+64 since (+64)>>1 = +32 == 0 mod 4).
    const int r0  = tid >> 2;                                  // 0..63
    const int swc = ((tid & 3) ^ ((tid >> 3) & 3)) * 8;        // swizzled source col (elems)
    const size_t a_g0 = (size_t)(m0 + r0) * K_ + swc;
    const size_t a_g1 = (size_t)(m0 + r0 + 64) * K_ + swc;
    const size_t b_g0 = (size_t)(n0 + r0) * K_ + swc;
    const size_t b_g1 = (size_t)(n0 + r0 + 64) * K_ + swc;
    const int w512 = wave * 512;                // wave-uniform LDS base (1024B per wave)

    for (int k0 = 0; k0 < K_; k0 += BK) {
        async_copy16(Ah + a_g0 + k0, AsH + w512);
        async_copy16(Ah + a_g1 + k0, AsH + 2048 + w512);
        async_copy16(Al + a_g0 + k0, AsL + w512);
        async_copy16(Al + a_g1 + k0, AsL + 2048 + w512);
        async_copy16(Bh + b_g0 + k0, BsH + w512);
        async_copy16(Bh + b_g1 + k0, BsH + 2048 + w512);
        async_copy16(Bl + b_g0 + k0, BsL + w512);
        async_copy16(Bl + b_g1 + k0, BsL + 2048 + w512);
        __syncthreads();

        // fragments: [m-or-n block][k-slice of 16]
        bf16x8 ah[2][2], al[2][2], bh[2][2], bl[2][2];
#pragma unroll
        for (int mi = 0; mi < 2; mi++) {
            const int rowA = (waveM + mi * 32 + lr) * BK;
            const int rowB = (waveN + mi * 32 + lr) * BK;
#pragma unroll
            for (int ks = 0; ks < 2; ks++) {
                const int co = (((ks * 2 + kc) ^ sw) * 8);
                ah[mi][ks] = *(const bf16x8*)(AsH + rowA + co);
                al[mi][ks] = *(const bf16x8*)(AsL + rowA + co);
                bh[mi][ks] = *(const bf16x8*)(BsH + rowB + co);
                bl[mi][ks] = *(const bf16x8*)(BsL + rowB + co);
            }
        }
#pragma unroll
        for (int mi = 0; mi < 2; mi++)
#pragma unroll
            for (int ni = 0; ni < 2; ni++)
#pragma unroll
                for (int ks = 0; ks < 2; ks++) {
                    acc[mi][ni] = __builtin_amdgcn_mfma_f32_32x32x16_bf16(
                        ah[mi][ks], bh[ni][ks], acc[mi][ni], 0, 0, 0);
                    acc[mi][ni] = __builtin_amdgcn_mfma_f32_32x32x16_bf16(
                        ah[mi][ks], bl[ni][ks], acc[mi][ni], 0, 0, 0);
                    acc[mi][ni] = __builtin_amdgcn_mfma_f32_32x32x16_bf16(
                        al[mi][ks], bh[ni][ks], acc[mi][ni], 0, 0, 0);
                }
        __syncthreads();
    }

    // epilogue: 32x32 C/D layout: col = lane&31, row = (reg&3) + 8*(reg>>2) + 4*(lane>>5)
#pragma unroll
    for (int mi = 0; mi < 2; mi++) {
        const int mbase = m0 + waveM + mi * 32 + (lane >> 5) * 4;
#pragma unroll
        for (int ni = 0; ni < 2; ni++) {
            const int n = n0 + waveN + ni * 32 + (lane & 31);
#pragma unroll
            for (int r = 0; r < 16; r++) {
                const int m = mbase + (r & 3) + 8 * (r >> 2);
                C[(size_t)m * N_ + n] = __float2half(acc[mi][ni][r]);
            }
        }
    }
}

// ---------------- quad-cooperative recurrent scan ----------------
// 4 lanes per (b,j) chain, one gate per lane (g = lane&3: 0=f,1=i,2=o,3=z).
// Uniform per-lane math with folded constants:
//   sigmoid lanes: v = rcp(1 + 2^(mu*h + mq*q + c0)),            mu=-u*log2e
//   z lane:        v = 1 - 2*rcp(1 + 2^(mu*h + mq*q + c0)),      mu=+2u*log2e
// Gate values broadcast to all 4 lanes via DPP quad_perm (VALU-rate).
// PF=32 ring (R2: 16->32 was -43 us; scan is load-stall-bound at 1 wave/SIMD).

template<int CTRL>
__device__ __forceinline__ float qperm(float v) {
    return __builtin_bit_cast(float,
        __builtin_amdgcn_mov_dpp(__builtin_bit_cast(int, v), CTRL, 0xF, 0xF, true));
}

#define PF 32   // prefetch depth; over-prefetches harmlessly into adjacent ws region

__global__ __launch_bounds__(256)
void scan_kernel(const __half* __restrict__ pre,   // [B*T][2048] fp16, col = j*4+g
                 const float* __restrict__ uf_, const float* __restrict__ bf_,
                 const float* __restrict__ ui_, const float* __restrict__ bi_,
                 const float* __restrict__ uo_, const float* __restrict__ bo_,
                 const float* __restrict__ uc_, const float* __restrict__ bc_,
                 float* __restrict__ out) {
    const int tid   = blockIdx.x * 256 + threadIdx.x;
    const int g     = tid & 3;
    const int chain = tid >> 2;        // [0, 16384)
    const int j     = chain & 511;
    const int b     = chain >> 9;

    const float* up = (g == 0) ? uf_ : (g == 1) ? ui_ : (g == 2) ? uo_ : uc_;
    const float* bp = (g == 0) ? bf_ : (g == 1) ? bi_ : (g == 2) ? bo_ : bc_;
    const float u  = up[j];
    const float bb = bp[j];

    const float L2E = 1.44269504f;
    const bool  isz = (g == 3);
    const float mq  = isz ?  2.0f * L2E : -L2E;   // multiplies q (pre value)
    const float mu  = u * mq;                      // multiplies h
    const float c0  = bb * mq;                     // folded bias
    const float Av  = isz ? -2.0f : 1.0f;
    const float Bv  = isz ?  1.0f : 0.0f;
    const float K2  = 2.0f * L2E;                  // tanh(c) exponent scale

    const __half* p = pre + ((size_t)b * T_) * N_ + (size_t)j * 4 + g;
    float* o = out + ((size_t)b * T_) * H_ + j;

    float h = 0.0f, c = 0.0f;

    __half ring[PF];
#pragma unroll
    for (int i = 0; i < PF; i++)
        ring[i] = p[(size_t)i * N_];
    const __half* pl = p + (size_t)PF * N_;

#pragma unroll 32
    for (int t = 0; t < T_; ++t) {
        float qf = (float)ring[t & (PF - 1)];
        ring[t & (PF - 1)] = *pl;                 // over-prefetch past end: lands in ws, unused
        pl += (size_t)N_;

        float a    = __builtin_fmaf(qf, mq, c0);          // off h-chain
        float e    = __builtin_amdgcn_exp2f(__builtin_fmaf(h, mu, a));
        float s    = __builtin_amdgcn_rcpf(1.0f + e);
        float v    = __builtin_fmaf(Av, s, Bv);           // f/i/o sigmoid or z tanh

        float f  = qperm<0x00>(v);    // quad_perm [0,0,0,0]
        float ii = qperm<0x55>(v);    // [1,1,1,1]
        float oo = qperm<0xAA>(v);    // [2,2,2,2]
        float z  = qperm<0xFF>(v);    // [3,3,3,3]

        c = __builtin_fmaf(f, c, ii * z);

        float e2 = __builtin_amdgcn_exp2f(c * K2);
        float tc = __builtin_fmaf(-2.0f, __builtin_amdgcn_rcpf(1.0f + e2), 1.0f);
        h = oo * tc;

        if (g == 0)
            o[(size_t)t * H_] = h;
    }
}

// ---------------- launch ----------------

extern "C" void kernel_launch(void* const* d_in, const int* in_sizes, int n_in,
                              void* d_out, int out_size, void* d_ws, size_t ws_size,
                              hipStream_t stream) {
    const float* x  = (const float*)d_in[0];
    const float* Wf = (const float*)d_in[1];
    const float* uf = (const float*)d_in[2];
    const float* bf = (const float*)d_in[3];
    const float* Wi = (const float*)d_in[4];
    const float* ui = (const float*)d_in[5];
    const float* bi = (const float*)d_in[6];
    const float* Wo = (const float*)d_in[7];
    const float* uo = (const float*)d_in[8];
    const float* bo = (const float*)d_in[9];
    const float* Wc = (const float*)d_in[10];
    const float* uc = (const float*)d_in[11];
    const float* bc = (const float*)d_in[12];
    float* out = (float*)d_out;

    // ws layout: pre fp16 (256 MiB) | xh (64) | xl (64) | Wh (2) | Wl (2)  = 388 MiB
    const size_t preB = (size_t)B_ * T_ * N_ * 2;
    const size_t xB   = (size_t)B_ * T_ * K_ * 2;
    const size_t wB   = (size_t)N_ * K_ * 2;

    __half* pre = (__half*)d_ws;
    __bf16* xh  = (__bf16*)((char*)d_ws + preB);
    __bf16* xl  = (__bf16*)((char*)d_ws + preB + xB);
    __bf16* Wh  = (__bf16*)((char*)d_ws + preB + 2 * xB);
    __bf16* Wl  = (__bf16*)((char*)d_ws + preB + 2 * xB + wB);
    (void)ws_size; (void)wB;

    convert_x<<<(B_ * T_ * K_ / 4 + 255) / 256, 256, 0, stream>>>(x, xh, xl, B_ * T_ * K_ / 4);
    convert_w<<<(N_ * K_) / 256, 256, 0, stream>>>(Wf, Wi, Wo, Wc, Wh, Wl);

    // h_t, c_t outputs are zeros
    hipMemsetAsync((char*)d_out + (size_t)B_ * T_ * H_ * 4, 0,
                   2 * (size_t)B_ * H_ * 4, stream);

    gemm_bt<<<dim3(NWG), 256, 0, stream>>>(xh, xl, Wh, Wl, pre);

    scan_kernel<<<dim3(B_ * H_ * 4 / 256), 256, 0, stream>>>(
        pre, uf, bf, ui, bi, uo, bo, uc, bc, out);
}

// Round 4
// 798.897 us; speedup vs baseline: 1.0587x; 1.0587x over previous
//
#include <hip/hip_runtime.h>
#include <hip/hip_fp16.h>

// Problem constants (IndyLSTM: B=32, T=2048, I=H=512)
#define B_  32
#define T_  2048
#define H_  512
#define K_  512          // input size I (GEMM K)
#define N_  2048         // 4*H (GEMM N), column index n' = h*4 + g  (g: 0=f,1=i,2=o,3=c)

typedef __attribute__((ext_vector_type(8))) __bf16 bf16x8;
typedef __attribute__((ext_vector_type(4))) __bf16 bf16x4;
typedef __attribute__((ext_vector_type(4))) float  floatx4;

// ---------------- conversion kernels (split bf16: v = hi + lo, fp32-accurate) ----------------

__global__ void convert_x(const float* __restrict__ x,
                          __bf16* __restrict__ xh, __bf16* __restrict__ xl, int n4) {
    int i = blockIdx.x * blockDim.x + threadIdx.x;
    if (i < n4) {
        const float4 v = ((const float4*)x)[i];
        bf16x4 hi, lo;
        hi[0] = (__bf16)v.x; lo[0] = (__bf16)(v.x - (float)hi[0]);
        hi[1] = (__bf16)v.y; lo[1] = (__bf16)(v.y - (float)hi[1]);
        hi[2] = (__bf16)v.z; lo[2] = (__bf16)(v.z - (float)hi[2]);
        hi[3] = (__bf16)v.w; lo[3] = (__bf16)(v.w - (float)hi[3]);
        *(bf16x4*)(xh + 4 * (size_t)i) = hi;
        *(bf16x4*)(xl + 4 * (size_t)i) = lo;
    }
}

// Wt[n'][k] = W_g[k][h] with n' = h*4+g  (k-contiguous => "B^T" layout for GEMM)
__global__ void convert_w(const float* __restrict__ Wf, const float* __restrict__ Wi,
                          const float* __restrict__ Wo, const float* __restrict__ Wc,
                          __bf16* __restrict__ Wh, __bf16* __restrict__ Wl) {
    int o = blockIdx.x * blockDim.x + threadIdx.x;   // [0, N_*K_)
    int k = o & (K_ - 1);
    int n = o >> 9;          // n' in [0,2048)
    int g = n & 3, h = n >> 2;
    const float* W = (g == 0) ? Wf : (g == 1) ? Wi : (g == 2) ? Wo : Wc;
    float v = W[k * H_ + h];
    __bf16 hi = (__bf16)v;
    Wh[o] = hi;
    Wl[o] = (__bf16)(v - (float)hi);
}

// ---------------- split-bf16 MFMA GEMM ----------------
// C[m][n] = sum_k A[m][k]*Bt[n][k] with A ~ Ah+Al, Bt ~ Bh+Bl
// acc += Ah*Bh + Ah*Bl + Al*Bh   (fp32-accurate to ~2^-18 relative)
//
// Round-4: EXACT R2 gemm body (369 us, MfmaUtil 53%, bank-conflicts 0) —
// R3's 32x32 shape + re-derived swizzle regressed (conflicts returned, matrix-busy
// flat). Only the EPILOGUE changes: C is written in scan-transposed layout
//   preT[(b*32 + (n>>6))*T + t][n&63]
// so each scan wave streams a contiguous region (128B/step sequential) instead of
// 1024 scattered 4KB-stride streams.
#define BM 128
#define BN 128
#define BK 32

__device__ __forceinline__ void async_copy16(const __bf16* g, __bf16* l) {
    __builtin_amdgcn_global_load_lds(
        (const __attribute__((address_space(1))) void*)g,
        (__attribute__((address_space(3))) void*)l,
        16, 0, 0);
}

__global__ __launch_bounds__(256, 2)
void gemm_bt(const __bf16* __restrict__ Ah, const __bf16* __restrict__ Al,
             const __bf16* __restrict__ Bh, const __bf16* __restrict__ Bl,
             __half* __restrict__ C) {
    __shared__ __align__(16) __bf16 AsH[BM * BK];
    __shared__ __align__(16) __bf16 AsL[BM * BK];
    __shared__ __align__(16) __bf16 BsH[BN * BK];
    __shared__ __align__(16) __bf16 BsL[BN * BK];

    const int tid  = threadIdx.x;
    const int lane = tid & 63;
    const int wave = tid >> 6;

    const int ntiles = N_ / BN;                 // 16
    const int bm = blockIdx.x / ntiles;
    const int bn = blockIdx.x % ntiles;
    const int m0 = bm * BM, n0 = bn * BN;

    const int waveM = (wave & 1) * 64;
    const int waveN = (wave >> 1) * 64;
    const int lm = lane & 15;
    const int q  = lane >> 4;
    // read-side swizzle: chunk q -> q ^ ((row>>1)&3); row = ...+lm so only lm matters
    const int lks = (q ^ ((lm >> 1) & 3)) * 8;

    floatx4 acc[4][4] = {};

    // staging: tile = 512 x 16B chunks; thread handles chunks tid and tid+256.
    // chunk c -> row c>>2, lds col-chunk c&3; SOURCE col-chunk is XOR-swizzled
    // (same swizzle valid for rows r and r+64 since (+64)>>1 = +32 == 0 mod 4).
    const int r0  = tid >> 2;                                  // 0..63
    const int swc = ((tid & 3) ^ ((tid >> 3) & 3)) * 8;        // swizzled source col (elems)
    const size_t a_g0 = (size_t)(m0 + r0) * K_ + swc;
    const size_t a_g1 = (size_t)(m0 + r0 + 64) * K_ + swc;
    const size_t b_g0 = (size_t)(n0 + r0) * K_ + swc;
    const size_t b_g1 = (size_t)(n0 + r0 + 64) * K_ + swc;
    const int w512 = wave * 512;                // wave-uniform LDS base (1024B per wave)

    for (int k0 = 0; k0 < K_; k0 += BK) {
        async_copy16(Ah + a_g0 + k0, AsH + w512);
        async_copy16(Ah + a_g1 + k0, AsH + 2048 + w512);
        async_copy16(Al + a_g0 + k0, AsL + w512);
        async_copy16(Al + a_g1 + k0, AsL + 2048 + w512);
        async_copy16(Bh + b_g0 + k0, BsH + w512);
        async_copy16(Bh + b_g1 + k0, BsH + 2048 + w512);
        async_copy16(Bl + b_g0 + k0, BsL + w512);
        async_copy16(Bl + b_g1 + k0, BsL + 2048 + w512);
        __syncthreads();

        bf16x8 ah[4], al[4], bh[4], bl[4];
#pragma unroll
        for (int mi = 0; mi < 4; mi++) {
            ah[mi] = *(const bf16x8*)(AsH + (waveM + mi * 16 + lm) * BK + lks);
            al[mi] = *(const bf16x8*)(AsL + (waveM + mi * 16 + lm) * BK + lks);
        }
#pragma unroll
        for (int ni = 0; ni < 4; ni++) {
            bh[ni] = *(const bf16x8*)(BsH + (waveN + ni * 16 + lm) * BK + lks);
            bl[ni] = *(const bf16x8*)(BsL + (waveN + ni * 16 + lm) * BK + lks);
        }
#pragma unroll
        for (int mi = 0; mi < 4; mi++)
#pragma unroll
            for (int ni = 0; ni < 4; ni++) {
                acc[mi][ni] = __builtin_amdgcn_mfma_f32_16x16x32_bf16(
                    ah[mi], bh[ni], acc[mi][ni], 0, 0, 0);
                acc[mi][ni] = __builtin_amdgcn_mfma_f32_16x16x32_bf16(
                    ah[mi], bl[ni], acc[mi][ni], 0, 0, 0);
                acc[mi][ni] = __builtin_amdgcn_mfma_f32_16x16x32_bf16(
                    al[mi], bh[ni], acc[mi][ni], 0, 0, 0);
            }
        __syncthreads();
    }

    // epilogue: C/D layout col = lane&15, row = (lane>>4)*4 + r.
    // Store into scan-transposed layout: m = b*T + t, n -> (jb = n>>6, c64 = n&63);
    // preT element index = ((b*32 + jb)*T + t)*64 + c64.
    //   (same 2B/elem, 16-lane groups still 32B-contiguous in c64)
#pragma unroll
    for (int mi = 0; mi < 4; mi++) {
        const int m = m0 + waveM + mi * 16 + (lane >> 4) * 4;
#pragma unroll
        for (int ni = 0; ni < 4; ni++) {
            const int n = n0 + waveN + ni * 16 + lm;
            const int jb = n >> 6, c64 = n & 63;
#pragma unroll
            for (int r = 0; r < 4; r++) {
                const int mm = m + r;
                const int bb = mm >> 11;            // T_ = 2048
                const int tt = mm & (T_ - 1);
                C[((size_t)(bb * 32 + jb) * T_ + tt) * 64 + c64] =
                    __float2half(acc[mi][ni][r]);
            }
        }
    }
}

// ---------------- quad-cooperative recurrent scan ----------------
// 4 lanes per (b,j) chain, one gate per lane (g = lane&3: 0=f,1=i,2=o,3=z).
// Round-4: pre is TRANSPOSED to preT[wave][t][64] where wave = b*32 + jb and the
// 64 inner halfs are lane-ordered (lane = jq*4 + g, j = jb*16 + jq). Each wave
// streams a contiguous 256KB region at 128B/step — sequential DRAM pages instead
// of 1024 scattered 4KB-stride streams. Quad/DPP structure unchanged.
//
//   sigmoid lanes: v = rcp(1 + 2^(mu*h + mq*q + c0)),            mu=-u*log2e
//   z lane:        v = 1 - 2*rcp(1 + 2^(mu*h + mq*q + c0)),      mu=+2u*log2e

template<int CTRL>
__device__ __forceinline__ float qperm(float v) {
    return __builtin_bit_cast(float,
        __builtin_amdgcn_mov_dpp(__builtin_bit_cast(int, v), CTRL, 0xF, 0xF, true));
}

#define PF 32   // prefetch depth; over-prefetches harmlessly into adjacent ws region

__global__ __launch_bounds__(256)
void scan_kernel(const __half* __restrict__ pre,   // preT[1024][T_][64] fp16
                 const float* __restrict__ uf_, const float* __restrict__ bf_,
                 const float* __restrict__ ui_, const float* __restrict__ bi_,
                 const float* __restrict__ uo_, const float* __restrict__ bo_,
                 const float* __restrict__ uc_, const float* __restrict__ bc_,
                 float* __restrict__ out) {
    const int gtid = blockIdx.x * 256 + threadIdx.x;
    const int lane = gtid & 63;
    const int wv   = gtid >> 6;        // 0..1023 = b*32 + jb
    const int g    = lane & 3;
    const int jq   = lane >> 2;        // 0..15
    const int b    = wv >> 5;
    const int jb   = wv & 31;
    const int j    = jb * 16 + jq;

    const float* up = (g == 0) ? uf_ : (g == 1) ? ui_ : (g == 2) ? uo_ : uc_;
    const float* bp = (g == 0) ? bf_ : (g == 1) ? bi_ : (g == 2) ? bo_ : bc_;
    const float u  = up[j];
    const float bb = bp[j];

    const float L2E = 1.44269504f;
    const bool  isz = (g == 3);
    const float mq  = isz ?  2.0f * L2E : -L2E;   // multiplies q (pre value)
    const float mu  = u * mq;                      // multiplies h
    const float c0  = bb * mq;                     // folded bias
    const float Av  = isz ? -2.0f : 1.0f;
    const float Bv  = isz ?  1.0f : 0.0f;
    const float K2  = 2.0f * L2E;                  // tanh(c) exponent scale

    const __half* p = pre + (size_t)wv * T_ * 64 + lane;   // stride 64 halfs per t
    float* o = out + ((size_t)b * T_) * H_ + j;

    float h = 0.0f, c = 0.0f;

    __half ring[PF];
#pragma unroll
    for (int i = 0; i < PF; i++)
        ring[i] = p[(size_t)i * 64];
    const __half* pl = p + (size_t)PF * 64;

#pragma unroll 32
    for (int t = 0; t < T_; ++t) {
        float qf = (float)ring[t & (PF - 1)];
        ring[t & (PF - 1)] = *pl;                 // over-prefetch past end: lands in ws, unused
        pl += 64;

        float a    = __builtin_fmaf(qf, mq, c0);          // off h-chain
        float e    = __builtin_amdgcn_exp2f(__builtin_fmaf(h, mu, a));
        float s    = __builtin_amdgcn_rcpf(1.0f + e);
        float v    = __builtin_fmaf(Av, s, Bv);           // f/i/o sigmoid or z tanh

        float f  = qperm<0x00>(v);    // quad_perm [0,0,0,0]
        float ii = qperm<0x55>(v);    // [1,1,1,1]
        float oo = qperm<0xAA>(v);    // [2,2,2,2]
        float z  = qperm<0xFF>(v);    // [3,3,3,3]

        c = __builtin_fmaf(f, c, ii * z);

        float e2 = __builtin_amdgcn_exp2f(c * K2);
        float tc = __builtin_fmaf(-2.0f, __builtin_amdgcn_rcpf(1.0f + e2), 1.0f);
        h = oo * tc;

        if (g == 0)
            o[(size_t)t * H_] = h;
    }
}

// ---------------- launch ----------------

extern "C" void kernel_launch(void* const* d_in, const int* in_sizes, int n_in,
                              void* d_out, int out_size, void* d_ws, size_t ws_size,
                              hipStream_t stream) {
    const float* x  = (const float*)d_in[0];
    const float* Wf = (const float*)d_in[1];
    const float* uf = (const float*)d_in[2];
    const float* bf = (const float*)d_in[3];
    const float* Wi = (const float*)d_in[4];
    const float* ui = (const float*)d_in[5];
    const float* bi = (const float*)d_in[6];
    const float* Wo = (const float*)d_in[7];
    const float* uo = (const float*)d_in[8];
    const float* bo = (const float*)d_in[9];
    const float* Wc = (const float*)d_in[10];
    const float* uc = (const float*)d_in[11];
    const float* bc = (const float*)d_in[12];
    float* out = (float*)d_out;

    // ws layout: pre fp16 (256 MiB) | xh (64) | xl (64) | Wh (2) | Wl (2)  = 388 MiB
    const size_t preB = (size_t)B_ * T_ * N_ * 2;
    const size_t xB   = (size_t)B_ * T_ * K_ * 2;
    const size_t wB   = (size_t)N_ * K_ * 2;

    __half* pre = (__half*)d_ws;
    __bf16* xh  = (__bf16*)((char*)d_ws + preB);
    __bf16* xl  = (__bf16*)((char*)d_ws + preB + xB);
    __bf16* Wh  = (__bf16*)((char*)d_ws + preB + 2 * xB);
    __bf16* Wl  = (__bf16*)((char*)d_ws + preB + 2 * xB + wB);
    (void)ws_size; (void)wB;

    convert_x<<<(B_ * T_ * K_ / 4 + 255) / 256, 256, 0, stream>>>(x, xh, xl, B_ * T_ * K_ / 4);
    convert_w<<<(N_ * K_) / 256, 256, 0, stream>>>(Wf, Wi, Wo, Wc, Wh, Wl);

    // h_t, c_t outputs are zeros
    hipMemsetAsync((char*)d_out + (size_t)B_ * T_ * H_ * 4, 0,
                   2 * (size_t)B_ * H_ * 4, stream);

    const int M = B_ * T_;                                   // 65536
    gemm_bt<<<dim3((M / BM) * (N_ / BN)), 256, 0, stream>>>(xh, xl, Wh, Wl, pre);

    scan_kernel<<<dim3(B_ * H_ * 4 / 256), 256, 0, stream>>>(
        pre, uf, bf, ui, bi, uo, bo, uc, bc, out);
}

// Round 5
// 762.820 us; speedup vs baseline: 1.1088x; 1.0473x over previous
//
#include <hip/hip_runtime.h>
#include <hip/hip_fp16.h>

// Problem constants (IndyLSTM: B=32, T=2048, I=H=512)
#define B_  32
#define T_  2048
#define H_  512
#define K_  512          // input size I (GEMM K)
#define N_  2048         // 4*H (GEMM N), column index n' = h*4 + g  (g: 0=f,1=i,2=o,3=c)

typedef __attribute__((ext_vector_type(8))) __bf16   bf16x8;
typedef __attribute__((ext_vector_type(4))) __bf16   bf16x4;
typedef __attribute__((ext_vector_type(4))) float    floatx4;
typedef __attribute__((ext_vector_type(4))) _Float16 h16x4;
typedef __attribute__((ext_vector_type(8))) _Float16 h16x8;

// ---------------- conversion kernels (split bf16: v = hi + lo, fp32-accurate) ----------------

__global__ void convert_x(const float* __restrict__ x,
                          __bf16* __restrict__ xh, __bf16* __restrict__ xl, int n4) {
    int i = blockIdx.x * blockDim.x + threadIdx.x;
    if (i < n4) {
        const float4 v = ((const float4*)x)[i];
        bf16x4 hi, lo;
        hi[0] = (__bf16)v.x; lo[0] = (__bf16)(v.x - (float)hi[0]);
        hi[1] = (__bf16)v.y; lo[1] = (__bf16)(v.y - (float)hi[1]);
        hi[2] = (__bf16)v.z; lo[2] = (__bf16)(v.z - (float)hi[2]);
        hi[3] = (__bf16)v.w; lo[3] = (__bf16)(v.w - (float)hi[3]);
        *(bf16x4*)(xh + 4 * (size_t)i) = hi;
        *(bf16x4*)(xl + 4 * (size_t)i) = lo;
    }
}

// Wt[n'][k] = W_g[k][h] with n' = h*4+g  (k-contiguous => "B^T" layout for GEMM)
__global__ void convert_w(const float* __restrict__ Wf, const float* __restrict__ Wi,
                          const float* __restrict__ Wo, const float* __restrict__ Wc,
                          __bf16* __restrict__ Wh, __bf16* __restrict__ Wl) {
    int o = blockIdx.x * blockDim.x + threadIdx.x;   // [0, N_*K_)
    int k = o & (K_ - 1);
    int n = o >> 9;          // n' in [0,2048)
    int g = n & 3, h = n >> 2;
    const float* W = (g == 0) ? Wf : (g == 1) ? Wi : (g == 2) ? Wo : Wc;
    float v = W[k * H_ + h];
    __bf16 hi = (__bf16)v;
    Wh[o] = hi;
    Wl[o] = (__bf16)(v - (float)hi);
}

// ---------------- split-bf16 MFMA GEMM ----------------
// C[m][n] = sum_k A[m][k]*Bt[n][k] with A ~ Ah+Al, Bt ~ Bh+Bl
// acc += Ah*Bh + Ah*Bl + Al*Bh   (fp32-accurate to ~2^-18 relative)
//
// Round-5: gemm BODY frozen at R2 (369 us, MfmaUtil 53%, conflicts 0).
// Epilogue stores into t-grouped scan layout:
//   preT2 half-index(wave, t, lane) = wave*T*64 + (t>>3)*512 + lane*8 + (t&7)
//   with wave = b*32 + (n>>6), lane = n&63  (lane = jq*4+g, j = jb*16+jq)
// Per (mi,ni) the 4 acc values are 4 consecutive halfs -> one 8B vector store.
#define BM 128
#define BN 128
#define BK 32

__device__ __forceinline__ void async_copy16(const __bf16* g, __bf16* l) {
    __builtin_amdgcn_global_load_lds(
        (const __attribute__((address_space(1))) void*)g,
        (__attribute__((address_space(3))) void*)l,
        16, 0, 0);
}

__global__ __launch_bounds__(256, 2)
void gemm_bt(const __bf16* __restrict__ Ah, const __bf16* __restrict__ Al,
             const __bf16* __restrict__ Bh, const __bf16* __restrict__ Bl,
             __half* __restrict__ C) {
    __shared__ __align__(16) __bf16 AsH[BM * BK];
    __shared__ __align__(16) __bf16 AsL[BM * BK];
    __shared__ __align__(16) __bf16 BsH[BN * BK];
    __shared__ __align__(16) __bf16 BsL[BN * BK];

    const int tid  = threadIdx.x;
    const int lane = tid & 63;
    const int wave = tid >> 6;

    const int ntiles = N_ / BN;                 // 16
    const int bm = blockIdx.x / ntiles;
    const int bn = blockIdx.x % ntiles;
    const int m0 = bm * BM, n0 = bn * BN;

    const int waveM = (wave & 1) * 64;
    const int waveN = (wave >> 1) * 64;
    const int lm = lane & 15;
    const int q  = lane >> 4;
    // read-side swizzle: chunk q -> q ^ ((row>>1)&3); row = ...+lm so only lm matters
    const int lks = (q ^ ((lm >> 1) & 3)) * 8;

    floatx4 acc[4][4] = {};

    // staging: tile = 512 x 16B chunks; thread handles chunks tid and tid+256.
    // chunk c -> row c>>2, lds col-chunk c&3; SOURCE col-chunk is XOR-swizzled
    // (same swizzle valid for rows r and r+64 since (+64)>>1 = +32 == 0 mod 4).
    const int r0  = tid >> 2;                                  // 0..63
    const int swc = ((tid & 3) ^ ((tid >> 3) & 3)) * 8;        // swizzled source col (elems)
    const size_t a_g0 = (size_t)(m0 + r0) * K_ + swc;
    const size_t a_g1 = (size_t)(m0 + r0 + 64) * K_ + swc;
    const size_t b_g0 = (size_t)(n0 + r0) * K_ + swc;
    const size_t b_g1 = (size_t)(n0 + r0 + 64) * K_ + swc;
    const int w512 = wave * 512;                // wave-uniform LDS base (1024B per wave)

    for (int k0 = 0; k0 < K_; k0 += BK) {
        async_copy16(Ah + a_g0 + k0, AsH + w512);
        async_copy16(Ah + a_g1 + k0, AsH + 2048 + w512);
        async_copy16(Al + a_g0 + k0, AsL + w512);
        async_copy16(Al + a_g1 + k0, AsL + 2048 + w512);
        async_copy16(Bh + b_g0 + k0, BsH + w512);
        async_copy16(Bh + b_g1 + k0, BsH + 2048 + w512);
        async_copy16(Bl + b_g0 + k0, BsL + w512);
        async_copy16(Bl + b_g1 + k0, BsL + 2048 + w512);
        __syncthreads();

        bf16x8 ah[4], al[4], bh[4], bl[4];
#pragma unroll
        for (int mi = 0; mi < 4; mi++) {
            ah[mi] = *(const bf16x8*)(AsH + (waveM + mi * 16 + lm) * BK + lks);
            al[mi] = *(const bf16x8*)(AsL + (waveM + mi * 16 + lm) * BK + lks);
        }
#pragma unroll
        for (int ni = 0; ni < 4; ni++) {
            bh[ni] = *(const bf16x8*)(BsH + (waveN + ni * 16 + lm) * BK + lks);
            bl[ni] = *(const bf16x8*)(BsL + (waveN + ni * 16 + lm) * BK + lks);
        }
#pragma unroll
        for (int mi = 0; mi < 4; mi++)
#pragma unroll
            for (int ni = 0; ni < 4; ni++) {
                acc[mi][ni] = __builtin_amdgcn_mfma_f32_16x16x32_bf16(
                    ah[mi], bh[ni], acc[mi][ni], 0, 0, 0);
                acc[mi][ni] = __builtin_amdgcn_mfma_f32_16x16x32_bf16(
                    ah[mi], bl[ni], acc[mi][ni], 0, 0, 0);
                acc[mi][ni] = __builtin_amdgcn_mfma_f32_16x16x32_bf16(
                    al[mi], bh[ni], acc[mi][ni], 0, 0, 0);
            }
        __syncthreads();
    }

    // epilogue: C/D layout col = lane&15, row = (lane>>4)*4 + r.
    // t-grouped store: half-index = wave*T*64 + (t>>3)*512 + c64*8 + (t&7).
    // m base is a multiple of 4 and (m&7) in {0,4}, so r=0..3 stays within one
    // 8-half group -> 4 consecutive halfs -> single 8B store (8B-aligned).
#pragma unroll
    for (int mi = 0; mi < 4; mi++) {
        const int m  = m0 + waveM + mi * 16 + (lane >> 4) * 4;
        const int bb = m >> 11;             // T_ = 2048
        const int tt = m & (T_ - 1);
        const size_t toff = (size_t)(tt >> 3) * 512 + (tt & 7);
#pragma unroll
        for (int ni = 0; ni < 4; ni++) {
            const int n  = n0 + waveN + ni * 16 + lm;
            const int jb = n >> 6, c64 = n & 63;
            h16x4 hv;
#pragma unroll
            for (int r = 0; r < 4; r++)
                hv[r] = (_Float16)acc[mi][ni][r];
            *reinterpret_cast<h16x4*>(
                C + (size_t)(bb * 32 + jb) * (T_ * 64) + toff + c64 * 8) = hv;
        }
    }
}

// ---------------- quad-cooperative recurrent scan ----------------
// 4 lanes per (b,j) chain, one gate per lane (g = lane&3: 0=f,1=i,2=o,3=z).
// Round-5: vmem-instruction batching (scan runs at 1 wave/SIMD -> zero TLP, so
// per-instruction vmem cost is fully exposed; R4 showed stream locality is NOT
// the limiter):
//   - loads: pre is t-grouped (preT2[wave][t/8][lane][8]) -> one 16B load per
//     8 steps per lane (was one 2B load per step).
//   - stores: h is broadcast to all 4 quad lanes each step; lane g latches h at
//     step t%4==g (cndmask) and ALL 64 lanes store once per 4 steps (was an
//     exec-masked store every step). Same 64B-segment count, 1/4 the instrs.
//
//   sigmoid lanes: v = rcp(1 + 2^(mu*h + mq*q + c0)),            mu=-u*log2e
//   z lane:        v = 1 - 2*rcp(1 + 2^(mu*h + mq*q + c0)),      mu=+2u*log2e

template<int CTRL>
__device__ __forceinline__ float qperm(float v) {
    return __builtin_bit_cast(float,
        __builtin_amdgcn_mov_dpp(__builtin_bit_cast(int, v), CTRL, 0xF, 0xF, true));
}

#define PFG 4   // prefetch depth in 8-step groups (32 timesteps in flight)

__global__ __launch_bounds__(256)
void scan_kernel(const __half* __restrict__ pre,   // preT2[1024][T/8][64][8] fp16
                 const float* __restrict__ uf_, const float* __restrict__ bf_,
                 const float* __restrict__ ui_, const float* __restrict__ bi_,
                 const float* __restrict__ uo_, const float* __restrict__ bo_,
                 const float* __restrict__ uc_, const float* __restrict__ bc_,
                 float* __restrict__ out) {
    const int gtid = blockIdx.x * 256 + threadIdx.x;
    const int lane = gtid & 63;
    const int wv   = gtid >> 6;        // 0..1023 = b*32 + jb
    const int g    = lane & 3;
    const int jq   = lane >> 2;        // 0..15
    const int b    = wv >> 5;
    const int jb   = wv & 31;
    const int j    = jb * 16 + jq;

    const float* up = (g == 0) ? uf_ : (g == 1) ? ui_ : (g == 2) ? uo_ : uc_;
    const float* bp = (g == 0) ? bf_ : (g == 1) ? bi_ : (g == 2) ? bo_ : bc_;
    const float u  = up[j];
    const float bb = bp[j];

    const float L2E = 1.44269504f;
    const bool  isz = (g == 3);
    const float mq  = isz ?  2.0f * L2E : -L2E;   // multiplies q (pre value)
    const float mu  = u * mq;                      // multiplies h
    const float c0  = bb * mq;                     // folded bias
    const float Av  = isz ? -2.0f : 1.0f;
    const float Bv  = isz ?  1.0f : 0.0f;
    const float K2  = 2.0f * L2E;                  // tanh(c) exponent scale

    const __half* p = pre + (size_t)wv * T_ * 64 + (size_t)lane * 8;
    // lane-g time offset folded into the output pointer: this lane stores t%4==g
    float* o2 = out + ((size_t)b * T_ + g) * H_ + j;

    float h = 0.0f, c = 0.0f, hkeep = 0.0f;

    h16x8 ring[PFG];
#pragma unroll
    for (int i = 0; i < PFG; i++)
        ring[i] = *(const h16x8*)(p + (size_t)i * 512);
    const __half* pl = p + (size_t)PFG * 512;

#pragma unroll 4
    for (int tb = 0; tb < T_ / 8; ++tb) {
        h16x8 grp = ring[tb & (PFG - 1)];
        ring[tb & (PFG - 1)] = *(const h16x8*)pl;   // over-prefetch: lands in ws, unused
        pl += 512;

#pragma unroll
        for (int s = 0; s < 8; ++s) {
            float qf = (float)grp[s];

            float a    = __builtin_fmaf(qf, mq, c0);          // off h-chain
            float e    = __builtin_amdgcn_exp2f(__builtin_fmaf(h, mu, a));
            float sg   = __builtin_amdgcn_rcpf(1.0f + e);
            float v    = __builtin_fmaf(Av, sg, Bv);          // f/i/o sigmoid or z tanh

            float f  = qperm<0x00>(v);    // quad_perm [0,0,0,0]
            float ii = qperm<0x55>(v);    // [1,1,1,1]
            float oo = qperm<0xAA>(v);    // [2,2,2,2]
            float z  = qperm<0xFF>(v);    // [3,3,3,3]

            c = __builtin_fmaf(f, c, ii * z);

            float e2 = __builtin_amdgcn_exp2f(c * K2);
            float tc = __builtin_fmaf(-2.0f, __builtin_amdgcn_rcpf(1.0f + e2), 1.0f);
            h = oo * tc;

            hkeep = ((s & 3) == g) ? h : hkeep;               // latch own timestep
            if ((s & 3) == 3)                                  // compile-time condition
                o2[(size_t)(tb * 8 + (s - 3)) * H_] = hkeep;   // all 64 lanes store
        }
    }
}

// ---------------- launch ----------------

extern "C" void kernel_launch(void* const* d_in, const int* in_sizes, int n_in,
                              void* d_out, int out_size, void* d_ws, size_t ws_size,
                              hipStream_t stream) {
    const float* x  = (const float*)d_in[0];
    const float* Wf = (const float*)d_in[1];
    const float* uf = (const float*)d_in[2];
    const float* bf = (const float*)d_in[3];
    const float* Wi = (const float*)d_in[4];
    const float* ui = (const float*)d_in[5];
    const float* bi = (const float*)d_in[6];
    const float* Wo = (const float*)d_in[7];
    const float* uo = (const float*)d_in[8];
    const float* bo = (const float*)d_in[9];
    const float* Wc = (const float*)d_in[10];
    const float* uc = (const float*)d_in[11];
    const float* bc = (const float*)d_in[12];
    float* out = (float*)d_out;

    // ws layout: pre fp16 (256 MiB) | xh (64) | xl (64) | Wh (2) | Wl (2)  = 388 MiB
    const size_t preB = (size_t)B_ * T_ * N_ * 2;
    const size_t xB   = (size_t)B_ * T_ * K_ * 2;
    const size_t wB   = (size_t)N_ * K_ * 2;

    __half* pre = (__half*)d_ws;
    __bf16* xh  = (__bf16*)((char*)d_ws + preB);
    __bf16* xl  = (__bf16*)((char*)d_ws + preB + xB);
    __bf16* Wh  = (__bf16*)((char*)d_ws + preB + 2 * xB);
    __bf16* Wl  = (__bf16*)((char*)d_ws + preB + 2 * xB + wB);
    (void)ws_size; (void)wB;

    convert_x<<<(B_ * T_ * K_ / 4 + 255) / 256, 256, 0, stream>>>(x, xh, xl, B_ * T_ * K_ / 4);
    convert_w<<<(N_ * K_) / 256, 256, 0, stream>>>(Wf, Wi, Wo, Wc, Wh, Wl);

    // h_t, c_t outputs are zeros
    hipMemsetAsync((char*)d_out + (size_t)B_ * T_ * H_ * 4, 0,
                   2 * (size_t)B_ * H_ * 4, stream);

    const int M = B_ * T_;                                   // 65536
    gemm_bt<<<dim3((M / BM) * (N_ / BN)), 256, 0, stream>>>(xh, xl, Wh, Wl, pre);

    scan_kernel<<<dim3(B_ * H_ * 4 / 256), 256, 0, stream>>>(
        pre, uf, bf, ui, bi, uo, bo, uc, bc, out);
}

// Round 6
// 741.906 us; speedup vs baseline: 1.1400x; 1.0282x over previous
//
#include <hip/hip_runtime.h>
#include <hip/hip_fp16.h>

// Problem constants (IndyLSTM: B=32, T=2048, I=H=512)
#define B_  32
#define T_  2048
#define H_  512
#define K_  512          // input size I (GEMM K)
#define N_  2048         // 4*H (GEMM N), column index n' = h*4 + g  (g: 0=f,1=i,2=o,3=c)

typedef __attribute__((ext_vector_type(8))) __bf16   bf16x8;
typedef __attribute__((ext_vector_type(4))) __bf16   bf16x4;
typedef __attribute__((ext_vector_type(4))) float    floatx4;
typedef __attribute__((ext_vector_type(4))) _Float16 h16x4;
typedef __attribute__((ext_vector_type(8))) _Float16 h16x8;

// ---------------- conversion kernels (split bf16: v = hi + lo, fp32-accurate) ----------------

__global__ void convert_x(const float* __restrict__ x,
                          __bf16* __restrict__ xh, __bf16* __restrict__ xl, int n4) {
    int i = blockIdx.x * blockDim.x + threadIdx.x;
    if (i < n4) {
        const float4 v = ((const float4*)x)[i];
        bf16x4 hi, lo;
        hi[0] = (__bf16)v.x; lo[0] = (__bf16)(v.x - (float)hi[0]);
        hi[1] = (__bf16)v.y; lo[1] = (__bf16)(v.y - (float)hi[1]);
        hi[2] = (__bf16)v.z; lo[2] = (__bf16)(v.z - (float)hi[2]);
        hi[3] = (__bf16)v.w; lo[3] = (__bf16)(v.w - (float)hi[3]);
        *(bf16x4*)(xh + 4 * (size_t)i) = hi;
        *(bf16x4*)(xl + 4 * (size_t)i) = lo;
    }
}

// Wt[n'][k] = W_g[k][h] with n' = h*4+g  (k-contiguous => "B^T" layout for GEMM)
__global__ void convert_w(const float* __restrict__ Wf, const float* __restrict__ Wi,
                          const float* __restrict__ Wo, const float* __restrict__ Wc,
                          __bf16* __restrict__ Wh, __bf16* __restrict__ Wl) {
    int o = blockIdx.x * blockDim.x + threadIdx.x;   // [0, N_*K_)
    int k = o & (K_ - 1);
    int n = o >> 9;          // n' in [0,2048)
    int g = n & 3, h = n >> 2;
    const float* W = (g == 0) ? Wf : (g == 1) ? Wi : (g == 2) ? Wo : Wc;
    float v = W[k * H_ + h];
    __bf16 hi = (__bf16)v;
    Wh[o] = hi;
    Wl[o] = (__bf16)(v - (float)hi);
}

// ---------------- split-bf16 MFMA GEMM ----------------
// C[m][n] = sum_k A[m][k]*Bt[n][k] with A ~ Ah+Al, Bt ~ Bh+Bl
// acc += Ah*Bh + Ah*Bl + Al*Bh   (fp32-accurate to ~2^-18 relative)
//
// Round-6: gemm body + epilogue FROZEN at R5 (360 us, MfmaUtil 53%, conflicts 0).
// Only change: bm0 parameter so the GEMM is launched as TWO half-M dispatches
// (~180 us each) -> the scan dispatch becomes visible in rocprof top-5.
#define BM 128
#define BN 128
#define BK 32

__device__ __forceinline__ void async_copy16(const __bf16* g, __bf16* l) {
    __builtin_amdgcn_global_load_lds(
        (const __attribute__((address_space(1))) void*)g,
        (__attribute__((address_space(3))) void*)l,
        16, 0, 0);
}

__global__ __launch_bounds__(256, 2)
void gemm_bt(const __bf16* __restrict__ Ah, const __bf16* __restrict__ Al,
             const __bf16* __restrict__ Bh, const __bf16* __restrict__ Bl,
             __half* __restrict__ C, int bm0) {
    __shared__ __align__(16) __bf16 AsH[BM * BK];
    __shared__ __align__(16) __bf16 AsL[BM * BK];
    __shared__ __align__(16) __bf16 BsH[BN * BK];
    __shared__ __align__(16) __bf16 BsL[BN * BK];

    const int tid  = threadIdx.x;
    const int lane = tid & 63;
    const int wave = tid >> 6;

    const int ntiles = N_ / BN;                 // 16
    const int bm = bm0 + blockIdx.x / ntiles;
    const int bn = blockIdx.x % ntiles;
    const int m0 = bm * BM, n0 = bn * BN;

    const int waveM = (wave & 1) * 64;
    const int waveN = (wave >> 1) * 64;
    const int lm = lane & 15;
    const int q  = lane >> 4;
    // read-side swizzle: chunk q -> q ^ ((row>>1)&3); row = ...+lm so only lm matters
    const int lks = (q ^ ((lm >> 1) & 3)) * 8;

    floatx4 acc[4][4] = {};

    // staging: tile = 512 x 16B chunks; thread handles chunks tid and tid+256.
    // chunk c -> row c>>2, lds col-chunk c&3; SOURCE col-chunk is XOR-swizzled
    // (same swizzle valid for rows r and r+64 since (+64)>>1 = +32 == 0 mod 4).
    const int r0_  = tid >> 2;                                 // 0..63
    const int swc = ((tid & 3) ^ ((tid >> 3) & 3)) * 8;        // swizzled source col (elems)
    const size_t a_g0 = (size_t)(m0 + r0_) * K_ + swc;
    const size_t a_g1 = (size_t)(m0 + r0_ + 64) * K_ + swc;
    const size_t b_g0 = (size_t)(n0 + r0_) * K_ + swc;
    const size_t b_g1 = (size_t)(n0 + r0_ + 64) * K_ + swc;
    const int w512 = wave * 512;                // wave-uniform LDS base (1024B per wave)

    for (int k0 = 0; k0 < K_; k0 += BK) {
        async_copy16(Ah + a_g0 + k0, AsH + w512);
        async_copy16(Ah + a_g1 + k0, AsH + 2048 + w512);
        async_copy16(Al + a_g0 + k0, AsL + w512);
        async_copy16(Al + a_g1 + k0, AsL + 2048 + w512);
        async_copy16(Bh + b_g0 + k0, BsH + w512);
        async_copy16(Bh + b_g1 + k0, BsH + 2048 + w512);
        async_copy16(Bl + b_g0 + k0, BsL + w512);
        async_copy16(Bl + b_g1 + k0, BsL + 2048 + w512);
        __syncthreads();

        bf16x8 ah[4], al[4], bh[4], bl[4];
#pragma unroll
        for (int mi = 0; mi < 4; mi++) {
            ah[mi] = *(const bf16x8*)(AsH + (waveM + mi * 16 + lm) * BK + lks);
            al[mi] = *(const bf16x8*)(AsL + (waveM + mi * 16 + lm) * BK + lks);
        }
#pragma unroll
        for (int ni = 0; ni < 4; ni++) {
            bh[ni] = *(const bf16x8*)(BsH + (waveN + ni * 16 + lm) * BK + lks);
            bl[ni] = *(const bf16x8*)(BsL + (waveN + ni * 16 + lm) * BK + lks);
        }
#pragma unroll
        for (int mi = 0; mi < 4; mi++)
#pragma unroll
            for (int ni = 0; ni < 4; ni++) {
                acc[mi][ni] = __builtin_amdgcn_mfma_f32_16x16x32_bf16(
                    ah[mi], bh[ni], acc[mi][ni], 0, 0, 0);
                acc[mi][ni] = __builtin_amdgcn_mfma_f32_16x16x32_bf16(
                    ah[mi], bl[ni], acc[mi][ni], 0, 0, 0);
                acc[mi][ni] = __builtin_amdgcn_mfma_f32_16x16x32_bf16(
                    al[mi], bh[ni], acc[mi][ni], 0, 0, 0);
            }
        __syncthreads();
    }

    // epilogue: C/D layout col = lane&15, row = (lane>>4)*4 + r.
    // t-grouped store: half-index = wave*T*64 + (t>>3)*512 + c64*8 + (t&7).
#pragma unroll
    for (int mi = 0; mi < 4; mi++) {
        const int m  = m0 + waveM + mi * 16 + (lane >> 4) * 4;
        const int bb = m >> 11;             // T_ = 2048
        const int tt = m & (T_ - 1);
        const size_t toff = (size_t)(tt >> 3) * 512 + (tt & 7);
#pragma unroll
        for (int ni = 0; ni < 4; ni++) {
            const int n  = n0 + waveN + ni * 16 + lm;
            const int jb = n >> 6, c64 = n & 63;
            h16x4 hv;
#pragma unroll
            for (int r = 0; r < 4; r++)
                hv[r] = (_Float16)acc[mi][ni][r];
            *reinterpret_cast<h16x4*>(
                C + (size_t)(bb * 32 + jb) * (T_ * 64) + toff + c64 * 8) = hv;
        }
    }
}

// ---------------- quad-cooperative recurrent scan ----------------
// 4 lanes per (b,j) chain, one gate per lane (g = lane&3: 0=f,1=i,2=o,3=z).
// Round-6: NO ARRAYS — rule #20 defense. R2..R5 used a ring buffer indexed by
// (t & (PF-1)); if the pragma-unroll ever declined, every ring access became
// SCRATCH (localMem), the known 4-5x slowdown signature that matches the
// otherwise-inexplicable ~400 cy/step. Now: four NAMED h16x8 registers with a
// hand-rotated 4-deep pipeline (load->use distance = 24 steps), all element
// extractions with literal indices, latch-selects precomputed as named bools.
// Math/layout/stores identical to R5 -> bitwise-same results.
//
//   sigmoid lanes: v = rcp(1 + 2^(mu*h + mq*q + c0)),            mu=-u*log2e
//   z lane:        v = 1 - 2*rcp(1 + 2^(mu*h + mq*q + c0)),      mu=+2u*log2e

template<int CTRL>
__device__ __forceinline__ float qperm(float v) {
    return __builtin_bit_cast(float,
        __builtin_amdgcn_mov_dpp(__builtin_bit_cast(int, v), CTRL, 0xF, 0xF, true));
}

__global__ __launch_bounds__(256)
void scan_kernel(const __half* __restrict__ pre,   // preT2[1024][T/8][64][8] fp16
                 const float* __restrict__ uf_, const float* __restrict__ bf_,
                 const float* __restrict__ ui_, const float* __restrict__ bi_,
                 const float* __restrict__ uo_, const float* __restrict__ bo_,
                 const float* __restrict__ uc_, const float* __restrict__ bc_,
                 float* __restrict__ out) {
    const int gtid = blockIdx.x * 256 + threadIdx.x;
    const int lane = gtid & 63;
    const int wv   = gtid >> 6;        // 0..1023 = b*32 + jb
    const int g    = lane & 3;
    const int jq   = lane >> 2;        // 0..15
    const int b    = wv >> 5;
    const int jb   = wv & 31;
    const int j    = jb * 16 + jq;

    const float* up = (g == 0) ? uf_ : (g == 1) ? ui_ : (g == 2) ? uo_ : uc_;
    const float* bp = (g == 0) ? bf_ : (g == 1) ? bi_ : (g == 2) ? bo_ : bc_;
    const float u  = up[j];
    const float bb = bp[j];

    const float L2E = 1.44269504f;
    const bool  isz = (g == 3);
    const float mq  = isz ?  2.0f * L2E : -L2E;   // multiplies q (pre value)
    const float mu  = u * mq;                      // multiplies h
    const float c0  = bb * mq;                     // folded bias
    const float Av  = isz ? -2.0f : 1.0f;
    const float Bv  = isz ?  1.0f : 0.0f;
    const float K2  = 2.0f * L2E;                  // tanh(c) exponent scale

    // latch selectors (hoisted; per-lane constant masks)
    const bool sel0 = (g == 0), sel1 = (g == 1), sel2 = (g == 2), sel3 = (g == 3);

    const __half* p = pre + (size_t)wv * T_ * 64 + (size_t)lane * 8;
    // lane-g time offset folded into the output pointer: this lane stores t%4==g
    float* o2 = out + ((size_t)b * T_ + g) * H_ + j;

    float h = 0.0f, c = 0.0f, hkeep = 0.0f;

    // 4-deep named-register pipeline (no arrays -> no scratch possible)
    h16x8 r0 = *(const h16x8*)(p);
    h16x8 r1 = *(const h16x8*)(p + 512);
    h16x8 r2 = *(const h16x8*)(p + 1024);
    h16x8 r3 = *(const h16x8*)(p + 1536);
    const __half* pl = p + 2048;

#define STEP(hreg, s, tstore)                                                   \
    {                                                                           \
        float qf = (float)hreg[s];                                              \
        float a  = __builtin_fmaf(qf, mq, c0);                                  \
        float e  = __builtin_amdgcn_exp2f(__builtin_fmaf(h, mu, a));            \
        float sg = __builtin_amdgcn_rcpf(1.0f + e);                             \
        float v  = __builtin_fmaf(Av, sg, Bv);                                  \
        float f  = qperm<0x00>(v);                                              \
        float ii = qperm<0x55>(v);                                              \
        float oo = qperm<0xAA>(v);                                              \
        float z  = qperm<0xFF>(v);                                              \
        c = __builtin_fmaf(f, c, ii * z);                                       \
        float e2 = __builtin_amdgcn_exp2f(c * K2);                              \
        float tc = __builtin_fmaf(-2.0f,                                        \
                       __builtin_amdgcn_rcpf(1.0f + e2), 1.0f);                 \
        h = oo * tc;                                                            \
        hkeep = (((s) & 3) == 0 ? sel0 : ((s) & 3) == 1 ? sel1                  \
                 : ((s) & 3) == 2 ? sel2 : sel3) ? h : hkeep;                   \
        if (((s) & 3) == 3)                                                     \
            o2[(size_t)(tstore) * H_] = hkeep;                                  \
    }

#define STEP8(hreg, tb)                                                         \
    STEP(hreg, 0, 0) STEP(hreg, 1, 0) STEP(hreg, 2, 0)                          \
    STEP(hreg, 3, (tb) * 8)                                                     \
    STEP(hreg, 4, 0) STEP(hreg, 5, 0) STEP(hreg, 6, 0)                          \
    STEP(hreg, 7, (tb) * 8 + 4)

    for (int tb = 0; tb < T_ / 8; tb += 4) {
        STEP8(r0, tb + 0) r0 = *(const h16x8*)pl; pl += 512;
        STEP8(r1, tb + 1) r1 = *(const h16x8*)pl; pl += 512;
        STEP8(r2, tb + 2) r2 = *(const h16x8*)pl; pl += 512;
        STEP8(r3, tb + 3) r3 = *(const h16x8*)pl; pl += 512;
        // over-prefetch past end lands in adjacent ws region: valid mem, unused
    }
#undef STEP8
#undef STEP
}

// ---------------- launch ----------------

extern "C" void kernel_launch(void* const* d_in, const int* in_sizes, int n_in,
                              void* d_out, int out_size, void* d_ws, size_t ws_size,
                              hipStream_t stream) {
    const float* x  = (const float*)d_in[0];
    const float* Wf = (const float*)d_in[1];
    const float* uf = (const float*)d_in[2];
    const float* bf = (const float*)d_in[3];
    const float* Wi = (const float*)d_in[4];
    const float* ui = (const float*)d_in[5];
    const float* bi = (const float*)d_in[6];
    const float* Wo = (const float*)d_in[7];
    const float* uo = (const float*)d_in[8];
    const float* bo = (const float*)d_in[9];
    const float* Wc = (const float*)d_in[10];
    const float* uc = (const float*)d_in[11];
    const float* bc = (const float*)d_in[12];
    float* out = (float*)d_out;

    // ws layout: pre fp16 (256 MiB) | xh (64) | xl (64) | Wh (2) | Wl (2)  = 388 MiB
    const size_t preB = (size_t)B_ * T_ * N_ * 2;
    const size_t xB   = (size_t)B_ * T_ * K_ * 2;
    const size_t wB   = (size_t)N_ * K_ * 2;

    __half* pre = (__half*)d_ws;
    __bf16* xh  = (__bf16*)((char*)d_ws + preB);
    __bf16* xl  = (__bf16*)((char*)d_ws + preB + xB);
    __bf16* Wh  = (__bf16*)((char*)d_ws + preB + 2 * xB);
    __bf16* Wl  = (__bf16*)((char*)d_ws + preB + 2 * xB + wB);
    (void)ws_size; (void)wB;

    convert_x<<<(B_ * T_ * K_ / 4 + 255) / 256, 256, 0, stream>>>(x, xh, xl, B_ * T_ * K_ / 4);
    convert_w<<<(N_ * K_) / 256, 256, 0, stream>>>(Wf, Wi, Wo, Wc, Wh, Wl);

    // h_t, c_t outputs are zeros
    hipMemsetAsync((char*)d_out + (size_t)B_ * T_ * H_ * 4, 0,
                   2 * (size_t)B_ * H_ * 4, stream);

    const int M = B_ * T_;                                   // 65536
    const int halfgrid = (M / BM / 2) * (N_ / BN);           // 4096
    gemm_bt<<<dim3(halfgrid), 256, 0, stream>>>(xh, xl, Wh, Wl, pre, 0);
    gemm_bt<<<dim3(halfgrid), 256, 0, stream>>>(xh, xl, Wh, Wl, pre, M / BM / 2);

    scan_kernel<<<dim3(B_ * H_ * 4 / 256), 256, 0, stream>>>(
        pre, uf, bf, ui, bi, uo, bo, uc, bc, out);
}

// Round 8
// 549.162 us; speedup vs baseline: 1.5402x; 1.3510x over previous
//
#include <hip/hip_runtime.h>
#include <hip/hip_fp16.h>

// Problem constants (IndyLSTM: B=32, T=2048, I=H=512)
#define B_  32
#define T_  2048
#define H_  512
#define K_  512          // input size I (GEMM K)
#define N_  2048         // 4*H (GEMM N), column index n' = h*4 + g  (g: 0=f,1=i,2=o,3=c)

typedef __attribute__((ext_vector_type(4))) float    floatx4;
typedef __attribute__((ext_vector_type(4))) _Float16 h16x4;
typedef __attribute__((ext_vector_type(8))) _Float16 h16x8;

// ---------------- conversion kernels (fp32 -> fp16, RNE) ----------------
// Round-7/8: single-f16 GEMM. The old split-bf16 (3-MFMA, ~2^-18 rel) was precision
// overkill: absmax (2^-8, constant across all rounds) is set by the fp16 storage
// of `pre`, not by GEMM rounding. f16 inputs + fp32 MFMA accumulate give
// ~2.2e-4 RMS on pre — an order below the fp16-pre-storage error.

__global__ void convert_x(const float* __restrict__ x,
                          _Float16* __restrict__ xh, int n4) {
    int i = blockIdx.x * blockDim.x + threadIdx.x;
    if (i < n4) {
        const float4 v = ((const float4*)x)[i];
        h16x4 hv;
        hv[0] = (_Float16)v.x; hv[1] = (_Float16)v.y;
        hv[2] = (_Float16)v.z; hv[3] = (_Float16)v.w;
        *(h16x4*)(xh + 4 * (size_t)i) = hv;
    }
}

// Wt[n'][k] = W_g[k][h] with n' = h*4+g  (k-contiguous => "B^T" layout for GEMM)
__global__ void convert_w(const float* __restrict__ Wf, const float* __restrict__ Wi,
                          const float* __restrict__ Wo, const float* __restrict__ Wc,
                          _Float16* __restrict__ Wh) {
    int o = blockIdx.x * blockDim.x + threadIdx.x;   // [0, N_*K_)
    int k = o & (K_ - 1);
    int n = o >> 9;          // n' in [0,2048)
    int g = n & 3, h = n >> 2;
    const float* W = (g == 0) ? Wf : (g == 1) ? Wi : (g == 2) ? Wo : Wc;
    Wh[o] = (_Float16)W[k * H_ + h];
}

// ---------------- f16 MFMA GEMM ----------------
// C[m][n] = sum_k A[m][k]*Bt[n][k], f16 inputs, fp32 accumulate.
// Structure = the proven R2 skeleton (single-buffered 2-barrier K-loop,
// global_load_lds staging with source-side XOR swizzle, read-side XOR swizzle,
// zero bank conflicts) with the L-arrays deleted: 2 LDS tiles (16 KB total),
// 4 async copies + 16 MFMA per K-iter. Epilogue: t-grouped 8B stores (R5).
#define BM 128
#define BN 128
#define BK 32

__device__ __forceinline__ void async_copy16(const void* g, void* l) {
    __builtin_amdgcn_global_load_lds(
        (const __attribute__((address_space(1))) void*)g,
        (__attribute__((address_space(3))) void*)l,
        16, 0, 0);
}

__global__ __launch_bounds__(256, 2)
void gemm_bt(const _Float16* __restrict__ A, const _Float16* __restrict__ Bt,
             __half* __restrict__ C) {
    __shared__ __align__(16) _Float16 As[BM * BK];
    __shared__ __align__(16) _Float16 Bs[BN * BK];

    const int tid  = threadIdx.x;
    const int lane = tid & 63;
    const int wave = tid >> 6;

    const int ntiles = N_ / BN;                 // 16
    const int bm = blockIdx.x / ntiles;
    const int bn = blockIdx.x % ntiles;
    const int m0 = bm * BM, n0 = bn * BN;

    const int waveM = (wave & 1) * 64;
    const int waveN = (wave >> 1) * 64;
    const int lm = lane & 15;
    const int q  = lane >> 4;
    // read-side swizzle: chunk q -> q ^ ((row>>1)&3); row = ...+lm so only lm matters
    const int lks = (q ^ ((lm >> 1) & 3)) * 8;

    floatx4 acc[4][4] = {};

    // staging: tile = 512 x 16B chunks; thread handles chunks tid and tid+256.
    // chunk c -> row c>>2, lds col-chunk c&3; SOURCE col-chunk is XOR-swizzled
    // (same swizzle valid for rows r and r+64 since (+64)>>1 = +32 == 0 mod 4).
    const int r0_ = tid >> 2;                                  // 0..63
    const int swc = ((tid & 3) ^ ((tid >> 3) & 3)) * 8;        // swizzled source col (elems)
    const size_t a_g0 = (size_t)(m0 + r0_) * K_ + swc;
    const size_t a_g1 = (size_t)(m0 + r0_ + 64) * K_ + swc;
    const size_t b_g0 = (size_t)(n0 + r0_) * K_ + swc;
    const size_t b_g1 = (size_t)(n0 + r0_ + 64) * K_ + swc;
    const int w512 = wave * 512;                // wave-uniform LDS base (1024B per wave)

    for (int k0 = 0; k0 < K_; k0 += BK) {
        async_copy16(A + a_g0 + k0, As + w512);
        async_copy16(A + a_g1 + k0, As + 2048 + w512);
        async_copy16(Bt + b_g0 + k0, Bs + w512);
        async_copy16(Bt + b_g1 + k0, Bs + 2048 + w512);
        __syncthreads();

        h16x8 a[4], b[4];
#pragma unroll
        for (int mi = 0; mi < 4; mi++)
            a[mi] = *(const h16x8*)(As + (waveM + mi * 16 + lm) * BK + lks);
#pragma unroll
        for (int ni = 0; ni < 4; ni++)
            b[ni] = *(const h16x8*)(Bs + (waveN + ni * 16 + lm) * BK + lks);
#pragma unroll
        for (int mi = 0; mi < 4; mi++)
#pragma unroll
            for (int ni = 0; ni < 4; ni++)
                acc[mi][ni] = __builtin_amdgcn_mfma_f32_16x16x32_f16(
                    a[mi], b[ni], acc[mi][ni], 0, 0, 0);
        __syncthreads();
    }

    // epilogue: C/D layout col = lane&15, row = (lane>>4)*4 + r.
    // t-grouped store: half-index = wave*T*64 + (t>>3)*512 + c64*8 + (t&7).
    // m base multiple of 4, (m&7) in {0,4} -> r=0..3 is one 8B-aligned vector.
#pragma unroll
    for (int mi = 0; mi < 4; mi++) {
        const int m  = m0 + waveM + mi * 16 + (lane >> 4) * 4;
        const int bb = m >> 11;             // T_ = 2048
        const int tt = m & (T_ - 1);
        const size_t toff = (size_t)(tt >> 3) * 512 + (tt & 7);
#pragma unroll
        for (int ni = 0; ni < 4; ni++) {
            const int n  = n0 + waveN + ni * 16 + lm;
            const int jb = n >> 6, c64 = n & 63;
            h16x4 hv;
#pragma unroll
            for (int r = 0; r < 4; r++)
                hv[r] = (_Float16)acc[mi][ni][r];
            *reinterpret_cast<h16x4*>(
                C + (size_t)(bb * 32 + jb) * (T_ * 64) + toff + c64 * 8) = hv;
        }
    }
}

// ---------------- quad-cooperative recurrent scan ----------------
// FROZEN at R6 (no-array named-register pipeline; rule #20 fix validated:
// scan dropped out of top-5, i.e. < 190 us, from ~340 us).
// 4 lanes per (b,j) chain, one gate per lane (g = lane&3: 0=f,1=i,2=o,3=z).
//   sigmoid lanes: v = rcp(1 + 2^(mu*h + mq*q + c0)),            mu=-u*log2e
//   z lane:        v = 1 - 2*rcp(1 + 2^(mu*h + mq*q + c0)),      mu=+2u*log2e

template<int CTRL>
__device__ __forceinline__ float qperm(float v) {
    return __builtin_bit_cast(float,
        __builtin_amdgcn_mov_dpp(__builtin_bit_cast(int, v), CTRL, 0xF, 0xF, true));
}

__global__ __launch_bounds__(256)
void scan_kernel(const __half* __restrict__ pre,   // preT2[1024][T/8][64][8] fp16
                 const float* __restrict__ uf_, const float* __restrict__ bf_,
                 const float* __restrict__ ui_, const float* __restrict__ bi_,
                 const float* __restrict__ uo_, const float* __restrict__ bo_,
                 const float* __restrict__ uc_, const float* __restrict__ bc_,
                 float* __restrict__ out) {
    const int gtid = blockIdx.x * 256 + threadIdx.x;
    const int lane = gtid & 63;
    const int wv   = gtid >> 6;        // 0..1023 = b*32 + jb
    const int g    = lane & 3;
    const int jq   = lane >> 2;        // 0..15
    const int b    = wv >> 5;
    const int jb   = wv & 31;
    const int j    = jb * 16 + jq;

    const float* up = (g == 0) ? uf_ : (g == 1) ? ui_ : (g == 2) ? uo_ : uc_;
    const float* bp = (g == 0) ? bf_ : (g == 1) ? bi_ : (g == 2) ? bo_ : bc_;
    const float u  = up[j];
    const float bb = bp[j];

    const float L2E = 1.44269504f;
    const bool  isz = (g == 3);
    const float mq  = isz ?  2.0f * L2E : -L2E;   // multiplies q (pre value)
    const float mu  = u * mq;                      // multiplies h
    const float c0  = bb * mq;                     // folded bias
    const float Av  = isz ? -2.0f : 1.0f;
    const float Bv  = isz ?  1.0f : 0.0f;
    const float K2  = 2.0f * L2E;                  // tanh(c) exponent scale

    // latch selectors (hoisted; per-lane constant masks)
    const bool sel0 = (g == 0), sel1 = (g == 1), sel2 = (g == 2), sel3 = (g == 3);

    const __half* p = pre + (size_t)wv * T_ * 64 + (size_t)lane * 8;
    // lane-g time offset folded into the output pointer: this lane stores t%4==g
    float* o2 = out + ((size_t)b * T_ + g) * H_ + j;

    float h = 0.0f, c = 0.0f, hkeep = 0.0f;

    // 4-deep named-register pipeline (no arrays -> no scratch possible)
    h16x8 r0 = *(const h16x8*)(p);
    h16x8 r1 = *(const h16x8*)(p + 512);
    h16x8 r2 = *(const h16x8*)(p + 1024);
    h16x8 r3 = *(const h16x8*)(p + 1536);
    const __half* pl = p + 2048;

#define STEP(hreg, s, tstore)                                                   \
    {                                                                           \
        float qf = (float)hreg[s];                                              \
        float a  = __builtin_fmaf(qf, mq, c0);                                  \
        float e  = __builtin_amdgcn_exp2f(__builtin_fmaf(h, mu, a));            \
        float sg = __builtin_amdgcn_rcpf(1.0f + e);                             \
        float v  = __builtin_fmaf(Av, sg, Bv);                                  \
        float f  = qperm<0x00>(v);                                              \
        float ii = qperm<0x55>(v);                                              \
        float oo = qperm<0xAA>(v);                                              \
        float z  = qperm<0xFF>(v);                                              \
        c = __builtin_fmaf(f, c, ii * z);                                       \
        float e2 = __builtin_amdgcn_exp2f(c * K2);                              \
        float tc = __builtin_fmaf(-2.0f,                                        \
                       __builtin_amdgcn_rcpf(1.0f + e2), 1.0f);                 \
        h = oo * tc;                                                            \
        hkeep = (((s) & 3) == 0 ? sel0 : ((s) & 3) == 1 ? sel1                  \
                 : ((s) & 3) == 2 ? sel2 : sel3) ? h : hkeep;                   \
        if (((s) & 3) == 3)                                                     \
            o2[(size_t)(tstore) * H_] = hkeep;                                  \
    }

#define STEP8(hreg, tb)                                                         \
    STEP(hreg, 0, 0) STEP(hreg, 1, 0) STEP(hreg, 2, 0)                          \
    STEP(hreg, 3, (tb) * 8)                                                     \
    STEP(hreg, 4, 0) STEP(hreg, 5, 0) STEP(hreg, 6, 0)                          \
    STEP(hreg, 7, (tb) * 8 + 4)

    for (int tb = 0; tb < T_ / 8; tb += 4) {
        STEP8(r0, tb + 0) r0 = *(const h16x8*)pl; pl += 512;
        STEP8(r1, tb + 1) r1 = *(const h16x8*)pl; pl += 512;
        STEP8(r2, tb + 2) r2 = *(const h16x8*)pl; pl += 512;
        STEP8(r3, tb + 3) r3 = *(const h16x8*)pl; pl += 512;
        // over-prefetch past end lands in adjacent ws region: valid mem, unused
    }
#undef STEP8
#undef STEP
}

// ---------------- launch ----------------

extern "C" void kernel_launch(void* const* d_in, const int* in_sizes, int n_in,
                              void* d_out, int out_size, void* d_ws, size_t ws_size,
                              hipStream_t stream) {
    const float* x  = (const float*)d_in[0];
    const float* Wf = (const float*)d_in[1];
    const float* uf = (const float*)d_in[2];
    const float* bf = (const float*)d_in[3];
    const float* Wi = (const float*)d_in[4];
    const float* ui = (const float*)d_in[5];
    const float* bi = (const float*)d_in[6];
    const float* Wo = (const float*)d_in[7];
    const float* uo = (const float*)d_in[8];
    const float* bo = (const float*)d_in[9];
    const float* Wc = (const float*)d_in[10];
    const float* uc = (const float*)d_in[11];
    const float* bc = (const float*)d_in[12];
    float* out = (float*)d_out;

    // ws layout: pre fp16 (256 MiB) | xh f16 (64 MiB) | Wh f16 (2 MiB)
    const size_t preB = (size_t)B_ * T_ * N_ * 2;
    const size_t xB   = (size_t)B_ * T_ * K_ * 2;

    __half*   pre = (__half*)d_ws;
    _Float16* xh  = (_Float16*)((char*)d_ws + preB);
    _Float16* Wh  = (_Float16*)((char*)d_ws + preB + xB);
    (void)ws_size;

    convert_x<<<(B_ * T_ * K_ / 4 + 255) / 256, 256, 0, stream>>>(x, xh, B_ * T_ * K_ / 4);
    convert_w<<<(N_ * K_) / 256, 256, 0, stream>>>(Wf, Wi, Wo, Wc, Wh);

    // h_t, c_t outputs are zeros
    hipMemsetAsync((char*)d_out + (size_t)B_ * T_ * H_ * 4, 0,
                   2 * (size_t)B_ * H_ * 4, stream);

    const int M = B_ * T_;                                   // 65536
    gemm_bt<<<dim3((M / BM) * (N_ / BN)), 256, 0, stream>>>(xh, Wh, pre);

    scan_kernel<<<dim3(B_ * H_ * 4 / 256), 256, 0, stream>>>(
        pre, uf, bf, ui, bi, uo, bo, uc, bc, out);
}